// Round 3
// baseline (674.662 us; speedup 1.0000x reference)
//
#include <hip/hip_runtime.h>
#include <hip/hip_bf16.h>

#define B_ 8
#define S_ 2048
#define H_ 256
#define Z_ 64
#define PS_LD 80   // Ps row stride in shorts: 160 B, keeps 16B alignment for all lanes

typedef short bf16x8 __attribute__((ext_vector_type(8)));
typedef float f32x4 __attribute__((ext_vector_type(4)));

__device__ __forceinline__ unsigned short f2bf(float f) {
  __hip_bfloat16 h = __float2bfloat16(f);
  return *reinterpret_cast<unsigned short*>(&h);
}
__device__ __forceinline__ float bf2f(unsigned short u) {
  __hip_bfloat16 h;
  *reinterpret_cast<unsigned short*>(&h) = u;
  return __bfloat162float(h);
}

// ---------------------------------------------------------------------------
// k0: per-batch encoder-part projections: q0/k0/v0[b][h] = sum_d enc[b][d]*W[d][h]
__global__ __launch_bounds__(256) void k0_base(
    const float* __restrict__ enc, const float* __restrict__ Wq,
    const float* __restrict__ Wk, const float* __restrict__ Wv,
    float* __restrict__ q0, float* __restrict__ k0, float* __restrict__ v0) {
  int b = blockIdx.x;
  int h = threadIdx.x;
  __shared__ float encs[H_];
  encs[h] = enc[b*H_ + h] + enc[B_*H_ + b*H_ + h];  // sum over 2 dirs
  __syncthreads();
  float aq = 0.f, ak = 0.f, av = 0.f;
  #pragma unroll 4
  for (int d = 0; d < H_; d++) {
    float e = encs[d];
    aq = fmaf(e, Wq[d*H_ + h], aq);
    ak = fmaf(e, Wk[d*H_ + h], ak);
    av = fmaf(e, Wv[d*H_ + h], av);
  }
  q0[b*H_ + h] = aq;
  k0[b*H_ + h] = ak;
  v0[b*H_ + h] = av;
}

// ---------------------------------------------------------------------------
// k1: z-part projection (fp32) + hi/lo bf16 split for Q,K; V -> bf16 transposed Vt[b][h][k]
__global__ __launch_bounds__(256) void k1_prep(
    const float* __restrict__ z, const float* __restrict__ Wq,
    const float* __restrict__ Wk, const float* __restrict__ Wv,
    const float* __restrict__ q0, const float* __restrict__ k0b, const float* __restrict__ v0,
    unsigned short* __restrict__ Qhi, unsigned short* __restrict__ Qlo,
    unsigned short* __restrict__ Khi, unsigned short* __restrict__ Klo,
    unsigned short* __restrict__ Vt) {
  int b  = blockIdx.x >> 7;   // 128 tiles of 16 s each
  int st = blockIdx.x & 127;
  int tid = threadIdx.x;      // tid = h
  __shared__ float zs[16*Z_];
  __shared__ float vbuf[16][H_];
  {
    const float4* zp = reinterpret_cast<const float4*>(z + ((size_t)b*S_ + st*16)*Z_);
    reinterpret_cast<float4*>(zs)[tid] = zp[tid];
  }
  __syncthreads();
  float bq = q0[b*H_ + tid], bk = k0b[b*H_ + tid], bv = v0[b*H_ + tid];
  float accq[16], acck[16], accv[16];
  #pragma unroll
  for (int s = 0; s < 16; s++) { accq[s] = bq; acck[s] = bk; accv[s] = bv; }
  for (int zi = 0; zi < Z_; zi++) {
    float wq = Wq[(H_+zi)*H_ + tid];
    float wk = Wk[(H_+zi)*H_ + tid];
    float wv = Wv[(H_+zi)*H_ + tid];
    #pragma unroll
    for (int s = 0; s < 16; s++) {
      float zz = zs[s*Z_ + zi];
      accq[s] = fmaf(zz, wq, accq[s]);
      acck[s] = fmaf(zz, wk, acck[s]);
      accv[s] = fmaf(zz, wv, accv[s]);
    }
  }
  #pragma unroll
  for (int s = 0; s < 16; s++) {
    size_t row = ((size_t)b*S_ + st*16 + s)*H_ + tid;
    unsigned short qh = f2bf(accq[s]);
    Qhi[row] = qh;
    Qlo[row] = f2bf(accq[s] - bf2f(qh));
    unsigned short kh = f2bf(acck[s]);
    Khi[row] = kh;
    Klo[row] = f2bf(acck[s] - bf2f(kh));
    vbuf[s][tid] = accv[s];
  }
  __syncthreads();
  // transpose V: thread h writes 16 consecutive k as bf16 (32B contiguous)
  unsigned int pk[8];
  #pragma unroll
  for (int j = 0; j < 8; j++) {
    pk[j] = (unsigned int)f2bf(vbuf[2*j][tid]) |
            ((unsigned int)f2bf(vbuf[2*j+1][tid]) << 16);
  }
  uint4* vt4 = reinterpret_cast<uint4*>(Vt + ((size_t)b*H_ + tid)*S_ + st*16);
  vt4[0] = make_uint4(pk[0], pk[1], pk[2], pk[3]);
  vt4[1] = make_uint4(pk[4], pk[5], pk[6], pk[7]);
}

// ---------------------------------------------------------------------------
// k2: flash attention. One wave = 16 q rows, full k sweep. Split-bf16 QK^T,
// online softmax, unnormalized p' -> attn buffer (fp32, fixed up later), bf16 AV.
__global__ __launch_bounds__(256) void k2_flash(
    const unsigned short* __restrict__ Qhi, const unsigned short* __restrict__ Qlo,
    const unsigned short* __restrict__ Khi, const unsigned short* __restrict__ Klo,
    const unsigned short* __restrict__ Vt, const int* __restrict__ mask,
    float* __restrict__ attn, float* __restrict__ outp,
    float* __restrict__ m_hist, float* __restrict__ m_final, float* __restrict__ inv_l) {
  int b    = blockIdx.x >> 5;   // 32 q-tiles of 64 per batch
  int qt   = blockIdx.x & 31;
  int tid  = threadIdx.x;
  int wave = tid >> 6;
  int lane = tid & 63;
  int l15  = lane & 15;
  int quad = lane >> 4;
  int qb   = qt*64 + wave*16;   // this wave's q base (within batch)

  // per-wave P tile; PS_LD=80 shorts (160 B) keeps every lane's bf16x8 read 16B-aligned
  __shared__ __align__(16) unsigned short Ps[4][16][PS_LD];

  // Q fragments: A[m=l15][k=quad*8+j], 8 d-chunks, hi+lo
  bf16x8 qh[8], ql[8];
  {
    const unsigned short* qhp = Qhi + ((size_t)b*S_ + qb + l15)*H_ + quad*8;
    const unsigned short* qlp = Qlo + ((size_t)b*S_ + qb + l15)*H_ + quad*8;
    #pragma unroll
    for (int dc = 0; dc < 8; dc++) {
      qh[dc] = *reinterpret_cast<const bf16x8*>(qhp + dc*32);
      ql[dc] = *reinterpret_cast<const bf16x8*>(qlp + dc*32);
    }
  }
  int mrow[4];
  #pragma unroll
  for (int r = 0; r < 4; r++) mrow[r] = mask[b*S_ + qb + quad*4 + r];

  f32x4 acc_o[16];
  #pragma unroll
  for (int ht = 0; ht < 16; ht++) acc_o[ht] = (f32x4){0.f, 0.f, 0.f, 0.f};
  float m_run[4] = {-1e30f, -1e30f, -1e30f, -1e30f};
  float l_run[4] = {0.f, 0.f, 0.f, 0.f};

  for (int ks = 0; ks < 32; ks++) {
    int kk0 = ks*64;
    // ---- S tile [16q x 64k] = Qhi*Khi + Qlo*Khi + Qhi*Klo ----
    f32x4 sacc[4];
    #pragma unroll
    for (int kt = 0; kt < 4; kt++) {
      f32x4 a = (f32x4){0.f, 0.f, 0.f, 0.f};
      const unsigned short* khp = Khi + ((size_t)b*S_ + kk0 + kt*16 + l15)*H_ + quad*8;
      const unsigned short* klp = Klo + ((size_t)b*S_ + kk0 + kt*16 + l15)*H_ + quad*8;
      #pragma unroll
      for (int dc = 0; dc < 8; dc++) {
        bf16x8 kh = *reinterpret_cast<const bf16x8*>(khp + dc*32);
        bf16x8 kl = *reinterpret_cast<const bf16x8*>(klp + dc*32);
        a = __builtin_amdgcn_mfma_f32_16x16x32_bf16(qh[dc], kh, a, 0, 0, 0);
        a = __builtin_amdgcn_mfma_f32_16x16x32_bf16(ql[dc], kh, a, 0, 0, 0);
        a = __builtin_amdgcn_mfma_f32_16x16x32_bf16(qh[dc], kl, a, 0, 0, 0);
      }
      sacc[kt] = a;
    }
    // ---- online softmax (rows = quad*4+r, cols across l15 lanes) ----
    float p[4][4];     // [kt][r]
    float alpha[4];
    #pragma unroll
    for (int r = 0; r < 4; r++) {
      float se[4];
      #pragma unroll
      for (int kt = 0; kt < 4; kt++)
        se[kt] = mrow[r] ? sacc[kt][r]*0.0625f : -1e9f;
      float ml = fmaxf(fmaxf(se[0], se[1]), fmaxf(se[2], se[3]));
      ml = fmaxf(ml, __shfl_xor(ml, 1));
      ml = fmaxf(ml, __shfl_xor(ml, 2));
      ml = fmaxf(ml, __shfl_xor(ml, 4));
      ml = fmaxf(ml, __shfl_xor(ml, 8));
      float mnew = fmaxf(m_run[r], ml);
      alpha[r] = __expf(m_run[r] - mnew);
      float ls = 0.f;
      #pragma unroll
      for (int kt = 0; kt < 4; kt++) { p[kt][r] = __expf(se[kt] - mnew); ls += p[kt][r]; }
      ls += __shfl_xor(ls, 1);
      ls += __shfl_xor(ls, 2);
      ls += __shfl_xor(ls, 4);
      ls += __shfl_xor(ls, 8);
      l_run[r] = l_run[r]*alpha[r] + ls;
      m_run[r] = mnew;
      if (l15 == 0)
        m_hist[((size_t)b*S_ + qb + quad*4 + r)*32 + ks] = mnew;
    }
    #pragma unroll
    for (int ht = 0; ht < 16; ht++) {
      acc_o[ht][0] *= alpha[0];
      acc_o[ht][1] *= alpha[1];
      acc_o[ht][2] *= alpha[2];
      acc_o[ht][3] *= alpha[3];
    }
    __syncthreads();   // WAR: previous iteration's Ps reads complete
    #pragma unroll
    for (int kt = 0; kt < 4; kt++) {
      #pragma unroll
      for (int r = 0; r < 4; r++) {
        // fp32 unnormalized p' to attn output region; bf16 copy to LDS for AV
        attn[((size_t)b*S_ + qb + quad*4 + r)*S_ + kk0 + kt*16 + l15] = p[kt][r];
        Ps[wave][quad*4 + r][kt*16 + l15] = f2bf(p[kt][r]);
      }
    }
    __syncthreads();
    // ---- AV: P (A-layout via LDS) x Vt (B-layout, k-contiguous 16B loads) ----
    bf16x8 pa0 = *reinterpret_cast<const bf16x8*>(&Ps[wave][l15][quad*8]);
    bf16x8 pa1 = *reinterpret_cast<const bf16x8*>(&Ps[wave][l15][32 + quad*8]);
    #pragma unroll
    for (int ht = 0; ht < 16; ht++) {
      const unsigned short* vp = Vt + ((size_t)b*H_ + ht*16 + l15)*S_ + kk0 + quad*8;
      bf16x8 v0f = *reinterpret_cast<const bf16x8*>(vp);
      bf16x8 v1f = *reinterpret_cast<const bf16x8*>(vp + 32);
      acc_o[ht] = __builtin_amdgcn_mfma_f32_16x16x32_bf16(pa0, v0f, acc_o[ht], 0, 0, 0);
      acc_o[ht] = __builtin_amdgcn_mfma_f32_16x16x32_bf16(pa1, v1f, acc_o[ht], 0, 0, 0);
    }
  }
  // ---- epilogue (fp32 out) ----
  float il[4];
  #pragma unroll
  for (int r = 0; r < 4; r++) il[r] = 1.f / l_run[r];
  #pragma unroll
  for (int ht = 0; ht < 16; ht++) {
    #pragma unroll
    for (int r = 0; r < 4; r++) {
      float o = acc_o[ht][r] * il[r];
      outp[((size_t)b*S_ + qb + quad*4 + r)*H_ + ht*16 + l15] = o;
    }
  }
  if (l15 == 0) {
    #pragma unroll
    for (int r = 0; r < 4; r++) {
      int q = b*S_ + qb + quad*4 + r;
      m_final[q] = m_run[r];
      inv_l[q]   = il[r];
    }
  }
}

// ---------------------------------------------------------------------------
// k3: attn[row][k] *= exp(m_hist[row][k/64] - m_final[row]) * inv_l[row]   (fp32)
__global__ __launch_bounds__(256) void k3_fixup(
    float* __restrict__ attn, const float* __restrict__ m_hist,
    const float* __restrict__ m_final, const float* __restrict__ inv_l) {
  int row = blockIdx.x;          // b*S_ + q  (one attn row per block)
  int tid = threadIdx.x;         // 8 floats per thread
  float mf = m_final[row];
  float il = inv_l[row];
  float f = __expf(m_hist[(size_t)row*32 + (tid >> 3)] - mf) * il;
  float4* p = reinterpret_cast<float4*>(attn + (size_t)row*S_ + tid*8);
  float4 v0 = p[0], v1 = p[1];
  v0.x *= f; v0.y *= f; v0.z *= f; v0.w *= f;
  v1.x *= f; v1.y *= f; v1.z *= f; v1.w *= f;
  p[0] = v0; p[1] = v1;
}

// ---------------------------------------------------------------------------
extern "C" void kernel_launch(void* const* d_in, const int* in_sizes, int n_in,
                              void* d_out, int out_size, void* d_ws, size_t ws_size,
                              hipStream_t stream) {
  const float* enc = (const float*)d_in[0];
  // d_in[1] = decoder_hidden_state: unused by the reference
  const float* z   = (const float*)d_in[2];
  const int* mask  = (const int*)d_in[3];
  const float* Wq  = (const float*)d_in[4];
  const float* Wk  = (const float*)d_in[5];
  const float* Wv  = (const float*)d_in[6];

  char* ws = (char*)d_ws;
  const size_t MB = 1024*1024;
  unsigned short* Qhi = (unsigned short*)(ws);
  unsigned short* Qlo = (unsigned short*)(ws +  8*MB);
  unsigned short* Khi = (unsigned short*)(ws + 16*MB);
  unsigned short* Klo = (unsigned short*)(ws + 24*MB);
  unsigned short* Vt  = (unsigned short*)(ws + 32*MB);
  float* m_hist  = (float*)(ws + 40*MB);                 // [B*S][32]
  float* m_final = (float*)(ws + 42*MB);                 // [B*S]
  float* inv_l   = (float*)(ws + 42*MB + 65536);         // [B*S]
  float* q0 = (float*)(ws + 42*MB + 2*65536);
  float* k0 = q0 + B_*H_;
  float* v0 = k0 + B_*H_;

  float* outp = (float*)d_out;                           // fp32 outputs
  float* attn = outp + (size_t)B_*S_*H_;

  k0_base<<<B_, 256, 0, stream>>>(enc, Wq, Wk, Wv, q0, k0, v0);
  k1_prep<<<B_*(S_/16), 256, 0, stream>>>(z, Wq, Wk, Wv, q0, k0, v0,
                                          Qhi, Qlo, Khi, Klo, Vt);
  k2_flash<<<B_*(S_/64), 256, 0, stream>>>(Qhi, Qlo, Khi, Klo, Vt, mask,
                                           attn, outp, m_hist, m_final, inv_l);
  k3_fixup<<<B_*S_, 256, 0, stream>>>(attn, m_hist, m_final, inv_l);
}

// Round 4
// 665.315 us; speedup vs baseline: 1.0140x; 1.0140x over previous
//
#include <hip/hip_runtime.h>
#include <hip/hip_bf16.h>

#define B_ 8
#define S_ 2048
#define H_ 256
#define Z_ 64
#define PS_LD 80   // Ps row stride in shorts: 160 B, keeps 16B alignment for all lanes

typedef short bf16x8 __attribute__((ext_vector_type(8)));
typedef float f32x4 __attribute__((ext_vector_type(4)));

__device__ __forceinline__ unsigned short f2bf(float f) {
  __hip_bfloat16 h = __float2bfloat16(f);
  return *reinterpret_cast<unsigned short*>(&h);
}
__device__ __forceinline__ float bf2f(unsigned short u) {
  __hip_bfloat16 h;
  *reinterpret_cast<unsigned short*>(&h) = u;
  return __bfloat162float(h);
}

// ---------------------------------------------------------------------------
// k0: per-batch encoder-part projections: q0/k0/v0[b][h] = sum_d enc[b][d]*W[d][h]
__global__ __launch_bounds__(256) void k0_base(
    const float* __restrict__ enc, const float* __restrict__ Wq,
    const float* __restrict__ Wk, const float* __restrict__ Wv,
    float* __restrict__ q0, float* __restrict__ k0, float* __restrict__ v0) {
  int b = blockIdx.x;
  int h = threadIdx.x;
  __shared__ float encs[H_];
  encs[h] = enc[b*H_ + h] + enc[B_*H_ + b*H_ + h];  // sum over 2 dirs
  __syncthreads();
  float aq = 0.f, ak = 0.f, av = 0.f;
  #pragma unroll 4
  for (int d = 0; d < H_; d++) {
    float e = encs[d];
    aq = fmaf(e, Wq[d*H_ + h], aq);
    ak = fmaf(e, Wk[d*H_ + h], ak);
    av = fmaf(e, Wv[d*H_ + h], av);
  }
  q0[b*H_ + h] = aq;
  k0[b*H_ + h] = ak;
  v0[b*H_ + h] = av;
}

// ---------------------------------------------------------------------------
// k1: z-part projection (fp32) + hi/lo bf16 split for Q,K; V -> bf16 transposed Vt[b][h][k]
__global__ __launch_bounds__(256) void k1_prep(
    const float* __restrict__ z, const float* __restrict__ Wq,
    const float* __restrict__ Wk, const float* __restrict__ Wv,
    const float* __restrict__ q0, const float* __restrict__ k0b, const float* __restrict__ v0,
    unsigned short* __restrict__ Qhi, unsigned short* __restrict__ Qlo,
    unsigned short* __restrict__ Khi, unsigned short* __restrict__ Klo,
    unsigned short* __restrict__ Vt) {
  int b  = blockIdx.x >> 7;   // 128 tiles of 16 s each
  int st = blockIdx.x & 127;
  int tid = threadIdx.x;      // tid = h
  __shared__ float zs[16*Z_];
  __shared__ float vbuf[16][H_];
  {
    const float4* zp = reinterpret_cast<const float4*>(z + ((size_t)b*S_ + st*16)*Z_);
    reinterpret_cast<float4*>(zs)[tid] = zp[tid];
  }
  __syncthreads();
  float bq = q0[b*H_ + tid], bk = k0b[b*H_ + tid], bv = v0[b*H_ + tid];
  float accq[16], acck[16], accv[16];
  #pragma unroll
  for (int s = 0; s < 16; s++) { accq[s] = bq; acck[s] = bk; accv[s] = bv; }
  for (int zi = 0; zi < Z_; zi++) {
    float wq = Wq[(H_+zi)*H_ + tid];
    float wk = Wk[(H_+zi)*H_ + tid];
    float wv = Wv[(H_+zi)*H_ + tid];
    #pragma unroll
    for (int s = 0; s < 16; s++) {
      float zz = zs[s*Z_ + zi];
      accq[s] = fmaf(zz, wq, accq[s]);
      acck[s] = fmaf(zz, wk, acck[s]);
      accv[s] = fmaf(zz, wv, accv[s]);
    }
  }
  #pragma unroll
  for (int s = 0; s < 16; s++) {
    size_t row = ((size_t)b*S_ + st*16 + s)*H_ + tid;
    unsigned short qh = f2bf(accq[s]);
    Qhi[row] = qh;
    Qlo[row] = f2bf(accq[s] - bf2f(qh));
    unsigned short kh = f2bf(acck[s]);
    Khi[row] = kh;
    Klo[row] = f2bf(acck[s] - bf2f(kh));
    vbuf[s][tid] = accv[s];
  }
  __syncthreads();
  // transpose V: thread h writes 16 consecutive k as bf16 (32B contiguous)
  unsigned int pk[8];
  #pragma unroll
  for (int j = 0; j < 8; j++) {
    pk[j] = (unsigned int)f2bf(vbuf[2*j][tid]) |
            ((unsigned int)f2bf(vbuf[2*j+1][tid]) << 16);
  }
  uint4* vt4 = reinterpret_cast<uint4*>(Vt + ((size_t)b*H_ + tid)*S_ + st*16);
  vt4[0] = make_uint4(pk[0], pk[1], pk[2], pk[3]);
  vt4[1] = make_uint4(pk[4], pk[5], pk[6], pk[7]);
}

// ---------------------------------------------------------------------------
// k2: flash attention, k-split x4. Block = 16 q rows; wave w sweeps k in
// [w*512, (w+1)*512). Tail: LDS combine of (m,l,acc_o) + in-block attn fixup.
__global__ __launch_bounds__(256, 3) void k2_flash(
    const unsigned short* __restrict__ Qhi, const unsigned short* __restrict__ Qlo,
    const unsigned short* __restrict__ Khi, const unsigned short* __restrict__ Klo,
    const unsigned short* __restrict__ Vt, const int* __restrict__ mask,
    float* __restrict__ attn, float* __restrict__ outp) {
  int b    = blockIdx.x >> 7;   // 128 strips of 16 q rows per batch
  int strip= blockIdx.x & 127;
  int qb   = strip*16;
  int tid  = threadIdx.x;
  int wave = tid >> 6;
  int lane = tid & 63;
  int l15  = lane & 15;
  int quad = lane >> 4;

  __shared__ __align__(16) unsigned short Ps[4][16][PS_LD]; // per-wave P tile
  __shared__ float mh[4][16][8];    // per-wave running max per 64-chunk
  __shared__ float Ml[4][16], Ll[4][16];
  __shared__ float Mf[16], Il[16];
  __shared__ float AccBuf[3][16][4][17];

  // Q fragments: A[m=l15][k=quad*8+j], 8 d-chunks, hi+lo (same for all waves)
  bf16x8 qh[8], ql[8];
  {
    const unsigned short* qhp = Qhi + ((size_t)b*S_ + qb + l15)*H_ + quad*8;
    const unsigned short* qlp = Qlo + ((size_t)b*S_ + qb + l15)*H_ + quad*8;
    #pragma unroll
    for (int dc = 0; dc < 8; dc++) {
      qh[dc] = *reinterpret_cast<const bf16x8*>(qhp + dc*32);
      ql[dc] = *reinterpret_cast<const bf16x8*>(qlp + dc*32);
    }
  }
  int mrow[4];
  #pragma unroll
  for (int r = 0; r < 4; r++) mrow[r] = mask[b*S_ + qb + quad*4 + r];

  f32x4 acc_o[16];
  #pragma unroll
  for (int ht = 0; ht < 16; ht++) acc_o[ht] = (f32x4){0.f, 0.f, 0.f, 0.f};
  float m_run[4] = {-1e30f, -1e30f, -1e30f, -1e30f};
  float l_run[4] = {0.f, 0.f, 0.f, 0.f};

  for (int ksl = 0; ksl < 8; ksl++) {
    int kk0 = (wave*8 + ksl)*64;
    // ---- S tile [16q x 64k] = Qhi*Khi + Qlo*Khi + Qhi*Klo ----
    f32x4 sacc[4];
    #pragma unroll
    for (int kt = 0; kt < 4; kt++) {
      f32x4 a = (f32x4){0.f, 0.f, 0.f, 0.f};
      const unsigned short* khp = Khi + ((size_t)b*S_ + kk0 + kt*16 + l15)*H_ + quad*8;
      const unsigned short* klp = Klo + ((size_t)b*S_ + kk0 + kt*16 + l15)*H_ + quad*8;
      #pragma unroll
      for (int dc = 0; dc < 8; dc++) {
        bf16x8 kh = *reinterpret_cast<const bf16x8*>(khp + dc*32);
        bf16x8 kl = *reinterpret_cast<const bf16x8*>(klp + dc*32);
        a = __builtin_amdgcn_mfma_f32_16x16x32_bf16(qh[dc], kh, a, 0, 0, 0);
        a = __builtin_amdgcn_mfma_f32_16x16x32_bf16(ql[dc], kh, a, 0, 0, 0);
        a = __builtin_amdgcn_mfma_f32_16x16x32_bf16(qh[dc], kl, a, 0, 0, 0);
      }
      sacc[kt] = a;
    }
    // ---- online softmax (rows = quad*4+r, cols across l15 lanes) ----
    float p[4][4];     // [kt][r]
    float alpha[4];
    #pragma unroll
    for (int r = 0; r < 4; r++) {
      float se[4];
      #pragma unroll
      for (int kt = 0; kt < 4; kt++)
        se[kt] = mrow[r] ? sacc[kt][r]*0.0625f : -1e9f;
      float ml = fmaxf(fmaxf(se[0], se[1]), fmaxf(se[2], se[3]));
      ml = fmaxf(ml, __shfl_xor(ml, 1));
      ml = fmaxf(ml, __shfl_xor(ml, 2));
      ml = fmaxf(ml, __shfl_xor(ml, 4));
      ml = fmaxf(ml, __shfl_xor(ml, 8));
      float mnew = fmaxf(m_run[r], ml);
      alpha[r] = __expf(m_run[r] - mnew);
      float ls = 0.f;
      #pragma unroll
      for (int kt = 0; kt < 4; kt++) { p[kt][r] = __expf(se[kt] - mnew); ls += p[kt][r]; }
      ls += __shfl_xor(ls, 1);
      ls += __shfl_xor(ls, 2);
      ls += __shfl_xor(ls, 4);
      ls += __shfl_xor(ls, 8);
      l_run[r] = l_run[r]*alpha[r] + ls;
      m_run[r] = mnew;
      if (l15 == 0) mh[wave][quad*4 + r][ksl] = mnew;
    }
    #pragma unroll
    for (int ht = 0; ht < 16; ht++) {
      acc_o[ht][0] *= alpha[0];
      acc_o[ht][1] *= alpha[1];
      acc_o[ht][2] *= alpha[2];
      acc_o[ht][3] *= alpha[3];
    }
    __syncthreads();   // WAR on Ps (all waves run identical trip counts)
    #pragma unroll
    for (int kt = 0; kt < 4; kt++) {
      #pragma unroll
      for (int r = 0; r < 4; r++) {
        // fp32 unnormalized p' to attn output region; bf16 copy to LDS for AV
        attn[((size_t)b*S_ + qb + quad*4 + r)*S_ + kk0 + kt*16 + l15] = p[kt][r];
        Ps[wave][quad*4 + r][kt*16 + l15] = f2bf(p[kt][r]);
      }
    }
    __syncthreads();
    // ---- AV: P (A-layout via LDS) x Vt (B-layout, k-contiguous 16B loads) ----
    bf16x8 pa0 = *reinterpret_cast<const bf16x8*>(&Ps[wave][l15][quad*8]);
    bf16x8 pa1 = *reinterpret_cast<const bf16x8*>(&Ps[wave][l15][32 + quad*8]);
    #pragma unroll
    for (int ht = 0; ht < 16; ht++) {
      const unsigned short* vp = Vt + ((size_t)b*H_ + ht*16 + l15)*S_ + kk0 + quad*8;
      bf16x8 v0f = *reinterpret_cast<const bf16x8*>(vp);
      bf16x8 v1f = *reinterpret_cast<const bf16x8*>(vp + 32);
      acc_o[ht] = __builtin_amdgcn_mfma_f32_16x16x32_bf16(pa0, v0f, acc_o[ht], 0, 0, 0);
      acc_o[ht] = __builtin_amdgcn_mfma_f32_16x16x32_bf16(pa1, v1f, acc_o[ht], 0, 0, 0);
    }
  }

  // ---- combine (m,l) across the 4 waves ----
  if (l15 == 0) {
    #pragma unroll
    for (int r = 0; r < 4; r++) {
      Ml[wave][quad*4 + r] = m_run[r];
      Ll[wave][quad*4 + r] = l_run[r];
    }
  }
  __syncthreads();
  float mf[4], il[4], ew[4];
  #pragma unroll
  for (int r = 0; r < 4; r++) {
    int row = quad*4 + r;
    float m0 = Ml[0][row], m1 = Ml[1][row], m2 = Ml[2][row], m3 = Ml[3][row];
    float m = fmaxf(fmaxf(m0, m1), fmaxf(m2, m3));
    float lf = Ll[0][row]*__expf(m0 - m) + Ll[1][row]*__expf(m1 - m)
             + Ll[2][row]*__expf(m2 - m) + Ll[3][row]*__expf(m3 - m);
    mf[r] = m;
    il[r] = 1.f / lf;
    ew[r] = __expf(m_run[r] - m);
  }
  if (wave == 0 && l15 == 0) {
    #pragma unroll
    for (int r = 0; r < 4; r++) { Mf[quad*4 + r] = mf[r]; Il[quad*4 + r] = il[r]; }
  }
  #pragma unroll
  for (int ht = 0; ht < 16; ht++) {
    acc_o[ht][0] *= ew[0];
    acc_o[ht][1] *= ew[1];
    acc_o[ht][2] *= ew[2];
    acc_o[ht][3] *= ew[3];
  }
  // ---- combine acc_o across waves (4 ht-groups of 4) and write outp ----
  for (int g = 0; g < 4; g++) {
    if (wave != 0) {
      #pragma unroll
      for (int hl = 0; hl < 4; hl++) {
        #pragma unroll
        for (int r = 0; r < 4; r++)
          AccBuf[wave-1][quad*4 + r][hl][l15] = acc_o[g*4 + hl][r];
      }
    }
    __syncthreads();
    if (wave == 0) {
      #pragma unroll
      for (int hl = 0; hl < 4; hl++) {
        int ht = g*4 + hl;
        #pragma unroll
        for (int r = 0; r < 4; r++) {
          int row = quad*4 + r;
          float o = acc_o[ht][r] + AccBuf[0][row][hl][l15]
                  + AccBuf[1][row][hl][l15] + AccBuf[2][row][hl][l15];
          outp[((size_t)b*S_ + qb + row)*H_ + ht*16 + l15] = o * il[r];
        }
      }
    }
    __syncthreads();
  }
  // ---- fixup this wave's attn columns: *= exp(mh - Mf[row]) * Il[row] ----
  // barriers above drained vmcnt, so main-loop p' stores are visible via L2.
  int ck = lane >> 3;                 // 64-chunk within this wave's range
  int c0 = wave*512 + lane*8;         // 8 contiguous fp32 per lane
  #pragma unroll 4
  for (int row = 0; row < 16; row++) {
    float f = __expf(mh[wave][row][ck] - Mf[row]) * Il[row];
    float4* pa = reinterpret_cast<float4*>(attn + ((size_t)b*S_ + qb + row)*S_ + c0);
    float4 x0 = pa[0], x1 = pa[1];
    x0.x *= f; x0.y *= f; x0.z *= f; x0.w *= f;
    x1.x *= f; x1.y *= f; x1.z *= f; x1.w *= f;
    pa[0] = x0; pa[1] = x1;
  }
}

// ---------------------------------------------------------------------------
extern "C" void kernel_launch(void* const* d_in, const int* in_sizes, int n_in,
                              void* d_out, int out_size, void* d_ws, size_t ws_size,
                              hipStream_t stream) {
  const float* enc = (const float*)d_in[0];
  // d_in[1] = decoder_hidden_state: unused by the reference
  const float* z   = (const float*)d_in[2];
  const int* mask  = (const int*)d_in[3];
  const float* Wq  = (const float*)d_in[4];
  const float* Wk  = (const float*)d_in[5];
  const float* Wv  = (const float*)d_in[6];

  char* ws = (char*)d_ws;
  const size_t MB = 1024*1024;
  unsigned short* Qhi = (unsigned short*)(ws);
  unsigned short* Qlo = (unsigned short*)(ws +  8*MB);
  unsigned short* Khi = (unsigned short*)(ws + 16*MB);
  unsigned short* Klo = (unsigned short*)(ws + 24*MB);
  unsigned short* Vt  = (unsigned short*)(ws + 32*MB);
  float* q0 = (float*)(ws + 40*MB);
  float* k0 = q0 + B_*H_;
  float* v0 = k0 + B_*H_;

  float* outp = (float*)d_out;                           // fp32 outputs
  float* attn = outp + (size_t)B_*S_*H_;

  k0_base<<<B_, 256, 0, stream>>>(enc, Wq, Wk, Wv, q0, k0, v0);
  k1_prep<<<B_*(S_/16), 256, 0, stream>>>(z, Wq, Wk, Wv, q0, k0, v0,
                                          Qhi, Qlo, Khi, Klo, Vt);
  k2_flash<<<B_*(S_/16), 256, 0, stream>>>(Qhi, Qlo, Khi, Klo, Vt, mask,
                                           attn, outp);
}

// Round 5
// 626.511 us; speedup vs baseline: 1.0769x; 1.0619x over previous
//
#include <hip/hip_runtime.h>
#include <hip/hip_bf16.h>

#define B_ 8
#define S_ 2048
#define H_ 256
#define Z_ 64
#define PS_LD 80   // Ps row stride in shorts: 160 B, keeps 16B alignment for all lanes

typedef short bf16x8 __attribute__((ext_vector_type(8)));
typedef float f32x4 __attribute__((ext_vector_type(4)));

__device__ __forceinline__ unsigned short f2bf(float f) {
  __hip_bfloat16 h = __float2bfloat16(f);
  return *reinterpret_cast<unsigned short*>(&h);
}
__device__ __forceinline__ float bf2f(unsigned short u) {
  __hip_bfloat16 h;
  *reinterpret_cast<unsigned short*>(&h) = u;
  return __bfloat162float(h);
}

// ---------------------------------------------------------------------------
// k0: per-batch encoder-part projections: q0/k0/v0[b][h] = sum_d enc[b][d]*W[d][h]
__global__ __launch_bounds__(256) void k0_base(
    const float* __restrict__ enc, const float* __restrict__ Wq,
    const float* __restrict__ Wk, const float* __restrict__ Wv,
    float* __restrict__ q0, float* __restrict__ k0, float* __restrict__ v0) {
  int b = blockIdx.x;
  int h = threadIdx.x;
  __shared__ float encs[H_];
  encs[h] = enc[b*H_ + h] + enc[B_*H_ + b*H_ + h];  // sum over 2 dirs
  __syncthreads();
  float aq = 0.f, ak = 0.f, av = 0.f;
  #pragma unroll 4
  for (int d = 0; d < H_; d++) {
    float e = encs[d];
    aq = fmaf(e, Wq[d*H_ + h], aq);
    ak = fmaf(e, Wk[d*H_ + h], ak);
    av = fmaf(e, Wv[d*H_ + h], av);
  }
  q0[b*H_ + h] = aq;
  k0[b*H_ + h] = ak;
  v0[b*H_ + h] = av;
}

// ---------------------------------------------------------------------------
// k1: z-part projection (fp32) + hi/lo bf16 split for Q,K; V -> bf16 transposed Vt[b][h][k]
__global__ __launch_bounds__(256) void k1_prep(
    const float* __restrict__ z, const float* __restrict__ Wq,
    const float* __restrict__ Wk, const float* __restrict__ Wv,
    const float* __restrict__ q0, const float* __restrict__ k0b, const float* __restrict__ v0,
    unsigned short* __restrict__ Qhi, unsigned short* __restrict__ Qlo,
    unsigned short* __restrict__ Khi, unsigned short* __restrict__ Klo,
    unsigned short* __restrict__ Vt) {
  int b  = blockIdx.x >> 7;   // 128 tiles of 16 s each
  int st = blockIdx.x & 127;
  int tid = threadIdx.x;      // tid = h
  __shared__ float zs[16*Z_];
  __shared__ float vbuf[16][H_];
  {
    const float4* zp = reinterpret_cast<const float4*>(z + ((size_t)b*S_ + st*16)*Z_);
    reinterpret_cast<float4*>(zs)[tid] = zp[tid];
  }
  __syncthreads();
  float bq = q0[b*H_ + tid], bk = k0b[b*H_ + tid], bv = v0[b*H_ + tid];
  float accq[16], acck[16], accv[16];
  #pragma unroll
  for (int s = 0; s < 16; s++) { accq[s] = bq; acck[s] = bk; accv[s] = bv; }
  for (int zi = 0; zi < Z_; zi++) {
    float wq = Wq[(H_+zi)*H_ + tid];
    float wk = Wk[(H_+zi)*H_ + tid];
    float wv = Wv[(H_+zi)*H_ + tid];
    #pragma unroll
    for (int s = 0; s < 16; s++) {
      float zz = zs[s*Z_ + zi];
      accq[s] = fmaf(zz, wq, accq[s]);
      acck[s] = fmaf(zz, wk, acck[s]);
      accv[s] = fmaf(zz, wv, accv[s]);
    }
  }
  #pragma unroll
  for (int s = 0; s < 16; s++) {
    size_t row = ((size_t)b*S_ + st*16 + s)*H_ + tid;
    unsigned short qh = f2bf(accq[s]);
    Qhi[row] = qh;
    Qlo[row] = f2bf(accq[s] - bf2f(qh));
    unsigned short kh = f2bf(acck[s]);
    Khi[row] = kh;
    Klo[row] = f2bf(acck[s] - bf2f(kh));
    vbuf[s][tid] = accv[s];
  }
  __syncthreads();
  // transpose V: thread h writes 16 consecutive k as bf16 (32B contiguous)
  unsigned int pk[8];
  #pragma unroll
  for (int j = 0; j < 8; j++) {
    pk[j] = (unsigned int)f2bf(vbuf[2*j][tid]) |
            ((unsigned int)f2bf(vbuf[2*j+1][tid]) << 16);
  }
  uint4* vt4 = reinterpret_cast<uint4*>(Vt + ((size_t)b*H_ + tid)*S_ + st*16);
  vt4[0] = make_uint4(pk[0], pk[1], pk[2], pk[3]);
  vt4[1] = make_uint4(pk[4], pk[5], pk[6], pk[7]);
}

// ---------------------------------------------------------------------------
// k2: flash attention, k-split x4. Block = 16 q rows; wave w sweeps k in
// [w*512, (w+1)*512). Main loop is barrier-free (Ps/mh/attn columns are
// wave-private); tail combines (m,l,acc_o) across waves + in-block fixup.
// launch_bounds(256,2): 256-reg budget -> no spills (R4: (256,3) forced
// VGPR=84 with scratch spills in the hot loop).
__global__ __launch_bounds__(256, 2) void k2_flash(
    const unsigned short* __restrict__ Qhi, const unsigned short* __restrict__ Qlo,
    const unsigned short* __restrict__ Khi, const unsigned short* __restrict__ Klo,
    const unsigned short* __restrict__ Vt, const int* __restrict__ mask,
    float* __restrict__ attn, float* __restrict__ outp) {
  int b    = blockIdx.x >> 7;   // 128 strips of 16 q rows per batch
  int strip= blockIdx.x & 127;
  int qb   = strip*16;
  int tid  = threadIdx.x;
  int wave = tid >> 6;
  int lane = tid & 63;
  int l15  = lane & 15;
  int quad = lane >> 4;

  __shared__ __align__(16) unsigned short Ps[4][16][PS_LD]; // per-wave P tile
  __shared__ float mh[4][16][8];    // per-wave running max per 64-chunk
  __shared__ float Ml[4][16], Ll[4][16];
  __shared__ float Mf[16], Il[16];
  __shared__ float AccBuf[3][16][4][17];

  // Q fragments: A[m=l15][k=quad*8+j], 8 d-chunks, hi+lo (same for all waves)
  bf16x8 qh[8], ql[8];
  {
    const unsigned short* qhp = Qhi + ((size_t)b*S_ + qb + l15)*H_ + quad*8;
    const unsigned short* qlp = Qlo + ((size_t)b*S_ + qb + l15)*H_ + quad*8;
    #pragma unroll
    for (int dc = 0; dc < 8; dc++) {
      qh[dc] = *reinterpret_cast<const bf16x8*>(qhp + dc*32);
      ql[dc] = *reinterpret_cast<const bf16x8*>(qlp + dc*32);
    }
  }
  int mrow[4];
  #pragma unroll
  for (int r = 0; r < 4; r++) mrow[r] = mask[b*S_ + qb + quad*4 + r];

  f32x4 acc_o[16];
  #pragma unroll
  for (int ht = 0; ht < 16; ht++) acc_o[ht] = (f32x4){0.f, 0.f, 0.f, 0.f};
  float m_run[4] = {-1e30f, -1e30f, -1e30f, -1e30f};
  float l_run[4] = {0.f, 0.f, 0.f, 0.f};

  for (int ksl = 0; ksl < 8; ksl++) {
    int kk0 = (wave*8 + ksl)*64;
    // ---- S tile [16q x 64k] = Qhi*Khi + Qlo*Khi + Qhi*Klo ----
    f32x4 sacc[4];
    #pragma unroll
    for (int kt = 0; kt < 4; kt++) {
      f32x4 a = (f32x4){0.f, 0.f, 0.f, 0.f};
      const unsigned short* khp = Khi + ((size_t)b*S_ + kk0 + kt*16 + l15)*H_ + quad*8;
      const unsigned short* klp = Klo + ((size_t)b*S_ + kk0 + kt*16 + l15)*H_ + quad*8;
      #pragma unroll
      for (int dc = 0; dc < 8; dc++) {
        bf16x8 kh = *reinterpret_cast<const bf16x8*>(khp + dc*32);
        bf16x8 kl = *reinterpret_cast<const bf16x8*>(klp + dc*32);
        a = __builtin_amdgcn_mfma_f32_16x16x32_bf16(qh[dc], kh, a, 0, 0, 0);
        a = __builtin_amdgcn_mfma_f32_16x16x32_bf16(ql[dc], kh, a, 0, 0, 0);
        a = __builtin_amdgcn_mfma_f32_16x16x32_bf16(qh[dc], kl, a, 0, 0, 0);
      }
      sacc[kt] = a;
    }
    // ---- online softmax (rows = quad*4+r, cols across l15 lanes) ----
    float p[4][4];     // [kt][r]
    float alpha[4];
    #pragma unroll
    for (int r = 0; r < 4; r++) {
      float se[4];
      #pragma unroll
      for (int kt = 0; kt < 4; kt++)
        se[kt] = mrow[r] ? sacc[kt][r]*0.0625f : -1e9f;
      float ml = fmaxf(fmaxf(se[0], se[1]), fmaxf(se[2], se[3]));
      ml = fmaxf(ml, __shfl_xor(ml, 1));
      ml = fmaxf(ml, __shfl_xor(ml, 2));
      ml = fmaxf(ml, __shfl_xor(ml, 4));
      ml = fmaxf(ml, __shfl_xor(ml, 8));
      float mnew = fmaxf(m_run[r], ml);
      alpha[r] = __expf(m_run[r] - mnew);
      float ls = 0.f;
      #pragma unroll
      for (int kt = 0; kt < 4; kt++) { p[kt][r] = __expf(se[kt] - mnew); ls += p[kt][r]; }
      ls += __shfl_xor(ls, 1);
      ls += __shfl_xor(ls, 2);
      ls += __shfl_xor(ls, 4);
      ls += __shfl_xor(ls, 8);
      l_run[r] = l_run[r]*alpha[r] + ls;
      m_run[r] = mnew;
      if (l15 == 0) mh[wave][quad*4 + r][ksl] = mnew;
    }
    #pragma unroll
    for (int ht = 0; ht < 16; ht++) {
      acc_o[ht][0] *= alpha[0];
      acc_o[ht][1] *= alpha[1];
      acc_o[ht][2] *= alpha[2];
      acc_o[ht][3] *= alpha[3];
    }
    // NO __syncthreads here: Ps[wave]/mh[wave]/attn columns are wave-private;
    // same-wave LDS ordering is via compiler-inserted lgkmcnt waits.
    #pragma unroll
    for (int kt = 0; kt < 4; kt++) {
      #pragma unroll
      for (int r = 0; r < 4; r++) {
        // fp32 unnormalized p' to attn output region; bf16 copy to LDS for AV
        attn[((size_t)b*S_ + qb + quad*4 + r)*S_ + kk0 + kt*16 + l15] = p[kt][r];
        Ps[wave][quad*4 + r][kt*16 + l15] = f2bf(p[kt][r]);
      }
    }
    // ---- AV: P (A-layout via LDS) x Vt (B-layout, k-contiguous 16B loads) ----
    bf16x8 pa0 = *reinterpret_cast<const bf16x8*>(&Ps[wave][l15][quad*8]);
    bf16x8 pa1 = *reinterpret_cast<const bf16x8*>(&Ps[wave][l15][32 + quad*8]);
    #pragma unroll
    for (int ht = 0; ht < 16; ht++) {
      const unsigned short* vp = Vt + ((size_t)b*H_ + ht*16 + l15)*S_ + kk0 + quad*8;
      bf16x8 v0f = *reinterpret_cast<const bf16x8*>(vp);
      bf16x8 v1f = *reinterpret_cast<const bf16x8*>(vp + 32);
      acc_o[ht] = __builtin_amdgcn_mfma_f32_16x16x32_bf16(pa0, v0f, acc_o[ht], 0, 0, 0);
      acc_o[ht] = __builtin_amdgcn_mfma_f32_16x16x32_bf16(pa1, v1f, acc_o[ht], 0, 0, 0);
    }
  }

  // ---- combine (m,l) across the 4 waves ----
  if (l15 == 0) {
    #pragma unroll
    for (int r = 0; r < 4; r++) {
      Ml[wave][quad*4 + r] = m_run[r];
      Ll[wave][quad*4 + r] = l_run[r];
    }
  }
  __syncthreads();
  float mf[4], il[4], ew[4];
  #pragma unroll
  for (int r = 0; r < 4; r++) {
    int row = quad*4 + r;
    float m0 = Ml[0][row], m1 = Ml[1][row], m2 = Ml[2][row], m3 = Ml[3][row];
    float m = fmaxf(fmaxf(m0, m1), fmaxf(m2, m3));
    float lf = Ll[0][row]*__expf(m0 - m) + Ll[1][row]*__expf(m1 - m)
             + Ll[2][row]*__expf(m2 - m) + Ll[3][row]*__expf(m3 - m);
    mf[r] = m;
    il[r] = 1.f / lf;
    ew[r] = __expf(m_run[r] - m);
  }
  if (wave == 0 && l15 == 0) {
    #pragma unroll
    for (int r = 0; r < 4; r++) { Mf[quad*4 + r] = mf[r]; Il[quad*4 + r] = il[r]; }
  }
  #pragma unroll
  for (int ht = 0; ht < 16; ht++) {
    acc_o[ht][0] *= ew[0];
    acc_o[ht][1] *= ew[1];
    acc_o[ht][2] *= ew[2];
    acc_o[ht][3] *= ew[3];
  }
  // ---- combine acc_o across waves (4 ht-groups of 4) and write outp ----
  for (int g = 0; g < 4; g++) {
    if (wave != 0) {
      #pragma unroll
      for (int hl = 0; hl < 4; hl++) {
        #pragma unroll
        for (int r = 0; r < 4; r++)
          AccBuf[wave-1][quad*4 + r][hl][l15] = acc_o[g*4 + hl][r];
      }
    }
    __syncthreads();
    if (wave == 0) {
      #pragma unroll
      for (int hl = 0; hl < 4; hl++) {
        int ht = g*4 + hl;
        #pragma unroll
        for (int r = 0; r < 4; r++) {
          int row = quad*4 + r;
          float o = acc_o[ht][r] + AccBuf[0][row][hl][l15]
                  + AccBuf[1][row][hl][l15] + AccBuf[2][row][hl][l15];
          outp[((size_t)b*S_ + qb + row)*H_ + ht*16 + l15] = o * il[r];
        }
      }
    }
    __syncthreads();
  }
  // ---- fixup this wave's attn columns: *= exp(mh - Mf[row]) * Il[row] ----
  int ck = lane >> 3;                 // 64-chunk within this wave's range
  int c0 = wave*512 + lane*8;         // 8 contiguous fp32 per lane
  #pragma unroll 4
  for (int row = 0; row < 16; row++) {
    float f = __expf(mh[wave][row][ck] - Mf[row]) * Il[row];
    float4* pa = reinterpret_cast<float4*>(attn + ((size_t)b*S_ + qb + row)*S_ + c0);
    float4 x0 = pa[0], x1 = pa[1];
    x0.x *= f; x0.y *= f; x0.z *= f; x0.w *= f;
    x1.x *= f; x1.y *= f; x1.z *= f; x1.w *= f;
    pa[0] = x0; pa[1] = x1;
  }
}

// ---------------------------------------------------------------------------
extern "C" void kernel_launch(void* const* d_in, const int* in_sizes, int n_in,
                              void* d_out, int out_size, void* d_ws, size_t ws_size,
                              hipStream_t stream) {
  const float* enc = (const float*)d_in[0];
  // d_in[1] = decoder_hidden_state: unused by the reference
  const float* z   = (const float*)d_in[2];
  const int* mask  = (const int*)d_in[3];
  const float* Wq  = (const float*)d_in[4];
  const float* Wk  = (const float*)d_in[5];
  const float* Wv  = (const float*)d_in[6];

  char* ws = (char*)d_ws;
  const size_t MB = 1024*1024;
  unsigned short* Qhi = (unsigned short*)(ws);
  unsigned short* Qlo = (unsigned short*)(ws +  8*MB);
  unsigned short* Khi = (unsigned short*)(ws + 16*MB);
  unsigned short* Klo = (unsigned short*)(ws + 24*MB);
  unsigned short* Vt  = (unsigned short*)(ws + 32*MB);
  float* q0 = (float*)(ws + 40*MB);
  float* k0 = q0 + B_*H_;
  float* v0 = k0 + B_*H_;

  float* outp = (float*)d_out;                           // fp32 outputs
  float* attn = outp + (size_t)B_*S_*H_;

  k0_base<<<B_, 256, 0, stream>>>(enc, Wq, Wk, Wv, q0, k0, v0);
  k1_prep<<<B_*(S_/16), 256, 0, stream>>>(z, Wq, Wk, Wv, q0, k0, v0,
                                          Qhi, Qlo, Khi, Klo, Vt);
  k2_flash<<<B_*(S_/16), 256, 0, stream>>>(Qhi, Qlo, Khi, Klo, Vt, mask,
                                           attn, outp);
}

// Round 6
// 453.103 us; speedup vs baseline: 1.4890x; 1.3827x over previous
//
#include <hip/hip_runtime.h>
#include <hip/hip_bf16.h>

#define B_ 8
#define S_ 2048
#define H_ 256
#define Z_ 64
#define CHK 32            // k-chunk staged per iteration
#define NCHK (S_/CHK)     // 64
#define KLD 264           // K LDS row stride (shorts) = 528 B; 528/16=33 odd -> conflict-free b128
#define VLD 40            // Vt/Ps LDS row stride (shorts) = 80 B; 80/16=5 odd -> conflict-free b128

typedef short bf16x8 __attribute__((ext_vector_type(8)));
typedef float f32x4 __attribute__((ext_vector_type(4)));

__device__ __forceinline__ unsigned short f2bf(float f) {
  __hip_bfloat16 h = __float2bfloat16(f);
  return *reinterpret_cast<unsigned short*>(&h);
}
__device__ __forceinline__ float bf2f(unsigned short u) {
  __hip_bfloat16 h;
  *reinterpret_cast<unsigned short*>(&h) = u;
  return __bfloat162float(h);
}

// ---------------------------------------------------------------------------
// k0: per-batch encoder-part projections: q0/k0/v0[b][h] = sum_d enc[b][d]*W[d][h]
__global__ __launch_bounds__(256) void k0_base(
    const float* __restrict__ enc, const float* __restrict__ Wq,
    const float* __restrict__ Wk, const float* __restrict__ Wv,
    float* __restrict__ q0, float* __restrict__ k0, float* __restrict__ v0) {
  int b = blockIdx.x;
  int h = threadIdx.x;
  __shared__ float encs[H_];
  encs[h] = enc[b*H_ + h] + enc[B_*H_ + b*H_ + h];  // sum over 2 dirs
  __syncthreads();
  float aq = 0.f, ak = 0.f, av = 0.f;
  #pragma unroll 4
  for (int d = 0; d < H_; d++) {
    float e = encs[d];
    aq = fmaf(e, Wq[d*H_ + h], aq);
    ak = fmaf(e, Wk[d*H_ + h], ak);
    av = fmaf(e, Wv[d*H_ + h], av);
  }
  q0[b*H_ + h] = aq;
  k0[b*H_ + h] = ak;
  v0[b*H_ + h] = av;
}

// ---------------------------------------------------------------------------
// k1: z-part projection (fp32) + hi/lo bf16 split for Q,K; V -> bf16 transposed Vt[b][h][k]
__global__ __launch_bounds__(256) void k1_prep(
    const float* __restrict__ z, const float* __restrict__ Wq,
    const float* __restrict__ Wk, const float* __restrict__ Wv,
    const float* __restrict__ q0, const float* __restrict__ k0b, const float* __restrict__ v0,
    unsigned short* __restrict__ Qhi, unsigned short* __restrict__ Qlo,
    unsigned short* __restrict__ Khi, unsigned short* __restrict__ Klo,
    unsigned short* __restrict__ Vt) {
  int b  = blockIdx.x >> 7;   // 128 tiles of 16 s each
  int st = blockIdx.x & 127;
  int tid = threadIdx.x;      // tid = h
  __shared__ float zs[16*Z_];
  __shared__ float vbuf[16][H_];
  {
    const float4* zp = reinterpret_cast<const float4*>(z + ((size_t)b*S_ + st*16)*Z_);
    reinterpret_cast<float4*>(zs)[tid] = zp[tid];
  }
  __syncthreads();
  float bq = q0[b*H_ + tid], bk = k0b[b*H_ + tid], bv = v0[b*H_ + tid];
  float accq[16], acck[16], accv[16];
  #pragma unroll
  for (int s = 0; s < 16; s++) { accq[s] = bq; acck[s] = bk; accv[s] = bv; }
  // zi-loop batched by 8 so the 24 weight loads issue together (R5: serialized
  // scalar loads at ~L2 latency made k1 latency-bound)
  #pragma unroll 2
  for (int z0 = 0; z0 < Z_; z0 += 8) {
    float wq[8], wk[8], wv[8];
    #pragma unroll
    for (int j = 0; j < 8; j++) {
      wq[j] = Wq[(H_+z0+j)*H_ + tid];
      wk[j] = Wk[(H_+z0+j)*H_ + tid];
      wv[j] = Wv[(H_+z0+j)*H_ + tid];
    }
    #pragma unroll
    for (int j = 0; j < 8; j++) {
      #pragma unroll
      for (int s = 0; s < 16; s++) {
        float zz = zs[s*Z_ + z0 + j];
        accq[s] = fmaf(zz, wq[j], accq[s]);
        acck[s] = fmaf(zz, wk[j], acck[s]);
        accv[s] = fmaf(zz, wv[j], accv[s]);
      }
    }
  }
  #pragma unroll
  for (int s = 0; s < 16; s++) {
    size_t row = ((size_t)b*S_ + st*16 + s)*H_ + tid;
    unsigned short qh = f2bf(accq[s]);
    Qhi[row] = qh;
    Qlo[row] = f2bf(accq[s] - bf2f(qh));
    unsigned short kh = f2bf(acck[s]);
    Khi[row] = kh;
    Klo[row] = f2bf(acck[s] - bf2f(kh));
    vbuf[s][tid] = accv[s];
  }
  __syncthreads();
  // transpose V: thread h writes 16 consecutive k as bf16 (32B contiguous)
  unsigned int pk[8];
  #pragma unroll
  for (int j = 0; j < 8; j++) {
    pk[j] = (unsigned int)f2bf(vbuf[2*j][tid]) |
            ((unsigned int)f2bf(vbuf[2*j+1][tid]) << 16);
  }
  uint4* vt4 = reinterpret_cast<uint4*>(Vt + ((size_t)b*H_ + tid)*S_ + st*16);
  vt4[0] = make_uint4(pk[0], pk[1], pk[2], pk[3]);
  vt4[1] = make_uint4(pk[4], pk[5], pk[6], pk[7]);
}

// ---------------------------------------------------------------------------
// k2: flash attention with shared double-buffered LDS K/V staging.
// Block = 64 q rows; wave w owns rows [w*16, w*16+16) and sweeps ALL k.
// Per chunk (32 k): cooperative staging of Khi/Klo/Vt into padded LDS
// (conflict-free b128 reads), split-bf16 QK, online softmax, fp32 p' store,
// bf16 AV. Tail: per-wave epilogue + in-place attn fixup (all state in LDS).
__global__ __launch_bounds__(256, 1) void k2_flash(
    const unsigned short* __restrict__ Qhi, const unsigned short* __restrict__ Qlo,
    const unsigned short* __restrict__ Khi, const unsigned short* __restrict__ Klo,
    const unsigned short* __restrict__ Vt, const int* __restrict__ mask,
    float* __restrict__ attn, float* __restrict__ outp) {
  int b    = blockIdx.x >> 5;   // 32 blocks of 64 q per batch
  int qt   = blockIdx.x & 31;
  int qb   = qt*64;
  int tid  = threadIdx.x;
  int wave = tid >> 6;
  int lane = tid & 63;
  int l15  = lane & 15;
  int quad = lane >> 4;
  int qw   = qb + wave*16;      // this wave's q base (within batch)

  __shared__ __align__(16) unsigned short KhiL[2][32*KLD];   // 33.0 KB
  __shared__ __align__(16) unsigned short KloL[2][32*KLD];   // 33.0 KB
  __shared__ __align__(16) unsigned short VtL [2][256*VLD];  // 40.0 KB
  __shared__ __align__(16) unsigned short Ps[4][16*VLD];     //  5.0 KB
  __shared__ float mh[4][16][NCHK];                          // 16.0 KB
  __shared__ float Mfin[4][16], Ilin[4][16];                 //  0.5 KB

  const unsigned short* KhiB = Khi + (size_t)b*S_*H_;
  const unsigned short* KloB = Klo + (size_t)b*S_*H_;
  const unsigned short* VtB  = Vt  + (size_t)b*H_*S_;

  uint4 rkh[4], rkl[4], rv[4];   // staging relay registers

  auto stage_issue = [&](int c) {
    int kc = c*CHK;
    const uint4* ph = reinterpret_cast<const uint4*>(KhiB + (size_t)kc*H_);
    const uint4* pl = reinterpret_cast<const uint4*>(KloB + (size_t)kc*H_);
    #pragma unroll
    for (int i = 0; i < 4; i++) {
      rkh[i] = ph[i*256 + tid];    // chunk is 16 KB contiguous
      rkl[i] = pl[i*256 + tid];
    }
    #pragma unroll
    for (int j = 0; j < 4; j++) {
      int h = j*64 + (tid>>2);
      rv[j] = *reinterpret_cast<const uint4*>(VtB + (size_t)h*S_ + kc + (tid&3)*8);
    }
  };
  auto stage_write = [&](int buf) {
    #pragma unroll
    for (int i = 0; i < 4; i++) {
      int idx = i*256 + tid;
      int row = idx >> 5, col = idx & 31;   // 32 x 16B per K row
      *reinterpret_cast<uint4*>(&KhiL[buf][row*KLD + col*8]) = rkh[i];
      *reinterpret_cast<uint4*>(&KloL[buf][row*KLD + col*8]) = rkl[i];
    }
    #pragma unroll
    for (int j = 0; j < 4; j++) {
      int h = j*64 + (tid>>2);
      *reinterpret_cast<uint4*>(&VtL[buf][h*VLD + (tid&3)*8]) = rv[j];
    }
  };

  // Q fragments: A[m=l15][k=quad*8+j], 8 d-chunks, hi+lo
  bf16x8 qh[8], ql[8];
  {
    const unsigned short* qhp = Qhi + ((size_t)b*S_ + qw + l15)*H_ + quad*8;
    const unsigned short* qlp = Qlo + ((size_t)b*S_ + qw + l15)*H_ + quad*8;
    #pragma unroll
    for (int dc = 0; dc < 8; dc++) {
      qh[dc] = *reinterpret_cast<const bf16x8*>(qhp + dc*32);
      ql[dc] = *reinterpret_cast<const bf16x8*>(qlp + dc*32);
    }
  }
  int mrow[4];
  #pragma unroll
  for (int r = 0; r < 4; r++) mrow[r] = mask[b*S_ + qw + quad*4 + r];

  f32x4 acc_o[16];
  #pragma unroll
  for (int ht = 0; ht < 16; ht++) acc_o[ht] = (f32x4){0.f, 0.f, 0.f, 0.f};
  float m_run[4] = {-1e30f, -1e30f, -1e30f, -1e30f};
  float l_run[4] = {0.f, 0.f, 0.f, 0.f};

  stage_issue(0);
  stage_write(0);
  __syncthreads();

  for (int c = 0; c < NCHK; c++) {
    if (c+1 < NCHK) stage_issue(c+1);   // loads land during compute below
    int buf = c & 1;
    int kc  = c*CHK;
    // ---- S tile [16q x 32k] = Qhi*Khi + Qlo*Khi + Qhi*Klo (K from LDS) ----
    f32x4 sacc[2];
    #pragma unroll
    for (int kt = 0; kt < 2; kt++) {
      f32x4 a = (f32x4){0.f, 0.f, 0.f, 0.f};
      #pragma unroll
      for (int dc = 0; dc < 8; dc++) {
        bf16x8 kh = *reinterpret_cast<const bf16x8*>(
            &KhiL[buf][(kt*16 + l15)*KLD + dc*32 + quad*8]);
        bf16x8 kl = *reinterpret_cast<const bf16x8*>(
            &KloL[buf][(kt*16 + l15)*KLD + dc*32 + quad*8]);
        a = __builtin_amdgcn_mfma_f32_16x16x32_bf16(qh[dc], kh, a, 0, 0, 0);
        a = __builtin_amdgcn_mfma_f32_16x16x32_bf16(ql[dc], kh, a, 0, 0, 0);
        a = __builtin_amdgcn_mfma_f32_16x16x32_bf16(qh[dc], kl, a, 0, 0, 0);
      }
      sacc[kt] = a;
    }
    // ---- online softmax (rows = quad*4+r, cols across l15 lanes) ----
    float p[2][4], alpha[4];
    #pragma unroll
    for (int r = 0; r < 4; r++) {
      float se0 = mrow[r] ? sacc[0][r]*0.0625f : -1e9f;
      float se1 = mrow[r] ? sacc[1][r]*0.0625f : -1e9f;
      float ml = fmaxf(se0, se1);
      ml = fmaxf(ml, __shfl_xor(ml, 1));
      ml = fmaxf(ml, __shfl_xor(ml, 2));
      ml = fmaxf(ml, __shfl_xor(ml, 4));
      ml = fmaxf(ml, __shfl_xor(ml, 8));
      float mnew = fmaxf(m_run[r], ml);
      alpha[r] = __expf(m_run[r] - mnew);
      p[0][r] = __expf(se0 - mnew);
      p[1][r] = __expf(se1 - mnew);
      float ls = p[0][r] + p[1][r];
      ls += __shfl_xor(ls, 1);
      ls += __shfl_xor(ls, 2);
      ls += __shfl_xor(ls, 4);
      ls += __shfl_xor(ls, 8);
      l_run[r] = l_run[r]*alpha[r] + ls;
      m_run[r] = mnew;
      if (l15 == 0) mh[wave][quad*4 + r][c] = mnew;
    }
    #pragma unroll
    for (int ht = 0; ht < 16; ht++) {
      acc_o[ht][0] *= alpha[0];
      acc_o[ht][1] *= alpha[1];
      acc_o[ht][2] *= alpha[2];
      acc_o[ht][3] *= alpha[3];
    }
    // ---- fp32 p' to attn; bf16 copy to Ps for the AV A-fragment ----
    #pragma unroll
    for (int kt = 0; kt < 2; kt++) {
      #pragma unroll
      for (int r = 0; r < 4; r++) {
        attn[((size_t)b*S_ + qw + quad*4 + r)*S_ + kc + kt*16 + l15] = p[kt][r];
        Ps[wave][(quad*4 + r)*VLD + kt*16 + l15] = f2bf(p[kt][r]);
      }
    }
    // ---- AV: P (A-layout via LDS) x Vt (B-layout from LDS) ----
    bf16x8 pa = *reinterpret_cast<const bf16x8*>(&Ps[wave][l15*VLD + quad*8]);
    #pragma unroll
    for (int ht = 0; ht < 16; ht++) {
      bf16x8 v = *reinterpret_cast<const bf16x8*>(
          &VtL[buf][(ht*16 + l15)*VLD + quad*8]);
      acc_o[ht] = __builtin_amdgcn_mfma_f32_16x16x32_bf16(pa, v, acc_o[ht], 0, 0, 0);
    }
    // ---- hand staged regs to the other buffer; one barrier per chunk ----
    if (c+1 < NCHK) stage_write((c+1) & 1);
    __syncthreads();
  }

  // ---- tail: epilogue + in-place attn fixup (wave-owned rows) ----
  float il[4];
  #pragma unroll
  for (int r = 0; r < 4; r++) il[r] = 1.f / l_run[r];
  if (l15 == 0) {
    #pragma unroll
    for (int r = 0; r < 4; r++) {
      Mfin[wave][quad*4 + r] = m_run[r];
      Ilin[wave][quad*4 + r] = il[r];
    }
  }
  #pragma unroll
  for (int ht = 0; ht < 16; ht++) {
    #pragma unroll
    for (int r = 0; r < 4; r++)
      outp[((size_t)b*S_ + qw + quad*4 + r)*H_ + ht*16 + l15] = acc_o[ht][r] * il[r];
  }
  // same-wave LDS visibility (lgkmcnt) is sufficient: Mfin/Ilin/mh[wave] are wave-private
  for (int row = 0; row < 16; row++) {
    float fm = Mfin[wave][row];
    float fi = Ilin[wave][row];
    float* rp = attn + ((size_t)b*S_ + qw + row)*S_;
    #pragma unroll
    for (int g = 0; g < 4; g++) {
      int chunk = g*16 + (lane >> 2);
      float f = __expf(mh[wave][row][chunk] - fm) * fi;
      float4* pa4 = reinterpret_cast<float4*>(rp + g*512 + lane*8);
      float4 x0 = pa4[0], x1 = pa4[1];
      x0.x *= f; x0.y *= f; x0.z *= f; x0.w *= f;
      x1.x *= f; x1.y *= f; x1.z *= f; x1.w *= f;
      pa4[0] = x0; pa4[1] = x1;
    }
  }
}

// ---------------------------------------------------------------------------
extern "C" void kernel_launch(void* const* d_in, const int* in_sizes, int n_in,
                              void* d_out, int out_size, void* d_ws, size_t ws_size,
                              hipStream_t stream) {
  const float* enc = (const float*)d_in[0];
  // d_in[1] = decoder_hidden_state: unused by the reference
  const float* z   = (const float*)d_in[2];
  const int* mask  = (const int*)d_in[3];
  const float* Wq  = (const float*)d_in[4];
  const float* Wk  = (const float*)d_in[5];
  const float* Wv  = (const float*)d_in[6];

  char* ws = (char*)d_ws;
  const size_t MB = 1024*1024;
  unsigned short* Qhi = (unsigned short*)(ws);
  unsigned short* Qlo = (unsigned short*)(ws +  8*MB);
  unsigned short* Khi = (unsigned short*)(ws + 16*MB);
  unsigned short* Klo = (unsigned short*)(ws + 24*MB);
  unsigned short* Vt  = (unsigned short*)(ws + 32*MB);
  float* q0 = (float*)(ws + 40*MB);
  float* k0 = q0 + B_*H_;
  float* v0 = k0 + B_*H_;

  float* outp = (float*)d_out;                           // fp32 outputs
  float* attn = outp + (size_t)B_*S_*H_;

  k0_base<<<B_, 256, 0, stream>>>(enc, Wq, Wk, Wv, q0, k0, v0);
  k1_prep<<<B_*(S_/16), 256, 0, stream>>>(z, Wq, Wk, Wv, q0, k0, v0,
                                          Qhi, Qlo, Khi, Klo, Vt);
  k2_flash<<<B_*(S_/64), 256, 0, stream>>>(Qhi, Qlo, Khi, Klo, Vt, mask,
                                           attn, outp);
}